// Round 6
// baseline (481.639 us; speedup 1.0000x reference)
//
#include <hip/hip_runtime.h>
#include <math.h>

// ---------------------------------------------------------------------------
// Fused 11-layer funnel MLP, round 8 (fix: B[10] typo in kernel_launch).
// Round-6/7 post-mortem: 32-row weight amortization is worth ~15us but can't
// be paid for with registers (r6: spill, +25MB scratch) or cross-wave
// barriers (r7: 15 barriers/chunk cost ~+20us). Round 5 remains best (84.8us,
// LDS pipe ~88% busy: 90 b128 reads + 40 writes per 16-row chunk).
// Round 8: remove the activation LDS round-trip entirely.
//  - v_mfma_f32_32x32x16_bf16: B covers 32 rows -> 32-row weight
//    amortization inside ONE wave; 1KB A-frag per 16384 MACs (2x fewer
//    LDS bytes/MAC than 16x16x32).
//  - Layer chaining in REGISTERS: C/D (col=lane&31, row=(reg&3)+8(reg>>2)
//    +4(lane>>5)) -> next B (col=lane&31, k=(lane>>5)*8+j) via
//    2x v_permlane32_swap + 4x v_cvt_pk_bf16_f32 per 32-chan tile
//    (pls(P0,P2)->(w0,w2), pls(P1,P3)->(w1,w3)). Pure VALU, no LDS.
//  - Tail NP widened to 32 so the m=OUT,OUT+1 generator rows ride inside
//    the tile: every transition uniform, bias scheme (hi/lo cols fed by
//    1.0-generator channels) unchanged.
//  - LDS = weights only (90KB, read-only, ONE barrier total). Per 32-row
//    chunk: 90 weight b128 reads, 0 act reads, 0 writes (~69k cy/CU vs
//    162k). Activations live in u32x4 frags, all statically indexed.
// ---------------------------------------------------------------------------

using bf16x8 = __attribute__((ext_vector_type(8))) short;   // 8 bf16 = 4 VGPRs
using f32x16 = __attribute__((ext_vector_type(16))) float;
using u32x2v = __attribute__((ext_vector_type(2))) unsigned;
using u32x4  = __attribute__((ext_vector_type(4))) unsigned;
typedef __bf16 bf16x2_t __attribute__((ext_vector_type(2)));

namespace {
constexpr int NL = 11;
constexpr int IN_[NL]   = {15, 30, 60, 90, 120, 90, 60, 30, 15, 10, 5};
constexpr int OUT_[NL]  = {30, 60, 90, 120, 90, 60, 30, 15, 10, 5, 1};
constexpr int KP_[NL]   = {32, 32, 64, 96, 128, 96, 64, 32, 32, 32, 32};  // in, pad 16-gran
constexpr int NP_[NL]   = {32, 64, 96, 128, 96, 64, 32, 32, 32, 32, 32};  // out, pad 32-gran
constexpr int WOFF_[NL] = {0, 1024, 3072, 9216, 21504, 33792, 39936,
                           41984, 43008, 44032, 45056};
constexpr int WTOT      = 46080;                     // shorts (90 KB)
constexpr int WAVES     = 16;
constexpr int THREADS   = WAVES * 64;                // 1024
constexpr int ROWS_PER_WAVE  = 32;
constexpr int ROWS_PER_BLOCK = WAVES * ROWS_PER_WAVE; // 512
constexpr int LDS_BYTES = WTOT * 2;                  // 92160
}

// fp32 -> bf16 RNE (scalar, staging only)
__device__ __forceinline__ unsigned short f2bf(float f) {
    unsigned u = __float_as_uint(f);
    u += 0x7fffu + ((u >> 16) & 1u);
    return (unsigned short)(u >> 16);
}

// packed fp32x2 -> bf16x2 (RNE); gfx950 has v_cvt_pk_bf16_f32
__device__ __forceinline__ unsigned pk2(float a, float b) {
#if __has_builtin(__builtin_amdgcn_cvt_pk_bf16_f32)
    return __builtin_bit_cast(unsigned, __builtin_amdgcn_cvt_pk_bf16_f32(a, b));
#else
    bf16x2_t c;
    c[0] = (__bf16)a;
    c[1] = (__bf16)b;
    return __builtin_bit_cast(unsigned, c);
#endif
}

// permlane32_swap: r[0] = [a_lo, b_lo], r[1] = [a_hi, b_hi]  (VALU, no LDS)
__device__ __forceinline__ u32x2v pls32(unsigned a, unsigned b) {
#if __has_builtin(__builtin_amdgcn_permlane32_swap)
    auto t = __builtin_amdgcn_permlane32_swap(a, b, false, false);
    u32x2v r;
    r[0] = t[0];
    r[1] = t[1];
    return r;
#else
    const int l = (int)(threadIdx.x & 63);
    unsigned bl = (unsigned)__shfl((int)b, l & 31, 64);
    unsigned ah = (unsigned)__shfl((int)a, l | 32, 64);
    u32x2v r;
    r[0] = (l < 32) ? a : bl;
    r[1] = (l < 32) ? ah : b;
    return r;
#endif
}

// Stage layer L's weights as 32x32x16 A-frags (frag-major, 512 shorts/frag).
// A[m][k]: lane = (k_local>>3)*32 + m_local, j = k_local&7.
// Bias folded as pad columns: k==IN -> bias_hi, k==IN+1 -> bias_lo.
// Generator rows m==OUT, OUT+1 emit 1.0 (feed next layer's bias columns).
template <int L>
__device__ __forceinline__ void stage_w(const float* __restrict__ W,
                                        const float* __restrict__ B,
                                        short* wlds, int tid) {
    constexpr int KP = KP_[L], NP = NP_[L], INl = IN_[L], OUTl = OUT_[L];
    constexpr int NKT = KP / 16;
    for (int idx = tid; idx < NP * KP; idx += THREADS) {
        const int f    = idx >> 9;
        const int t    = idx & 511;
        const int ln   = t >> 3;
        const int j    = t & 7;
        const int mloc = ln & 31;
        const int kh   = ln >> 5;
        const int mt   = f / NKT;
        const int kt   = f - mt * NKT;
        const int m    = mt * 32 + mloc;
        const int k    = kt * 16 + kh * 8 + j;
        float v = 0.f;
        if (m < OUTl) {
            if (k < INl) v = W[m * INl + k];
            else if (k == INl) v = B[m];                    // bias_hi
            else if (k == INl + 1) {                        // bias_lo
                float hf = __builtin_bit_cast(float, (unsigned)f2bf(B[m]) << 16);
                v = B[m] - hf;
            }
        } else if (m == OUTl || m == OUTl + 1) {
            if (k == INl) v = 1.f;                          // 1.0-generator row
        }
        wlds[WOFF_[L] + idx] = (short)f2bf(v);
    }
}

// One Linear+ReLU layer over this wave's 32 rows, fully in registers.
// bin: KP/16 input B-frags; bout: 2*NMT output B-frags (= next layer's bin).
template <int L>
__device__ __forceinline__ void layer(const short* __restrict__ wlds,
                                      const u32x4* bin, u32x4* bout, int lofs) {
    constexpr int NKT = KP_[L] / 16;
    constexpr int NMT = NP_[L] / 32;
    const short* wl = wlds + WOFF_[L];
#pragma unroll
    for (int mt = 0; mt < NMT; ++mt) {
        f32x16 acc;
#pragma unroll
        for (int i = 0; i < 16; ++i) acc[i] = 0.f;
#pragma unroll
        for (int kt = 0; kt < NKT; ++kt) {
            bf16x8 af = *(const bf16x8*)(wl + (mt * NKT + kt) * 512 + lofs);
            acc = __builtin_amdgcn_mfma_f32_32x32x16_bf16(
                af, __builtin_bit_cast(bf16x8, bin[kt]), acc, 0, 0, 0);
        }
        // ReLU + pack reg-pairs: P[i] covers rows (4h + pair) per group.
        unsigned P[8];
#pragma unroll
        for (int i = 0; i < 8; ++i)
            P[i] = pk2(fmaxf(acc[2 * i], 0.f), fmaxf(acc[2 * i + 1], 0.f));
        // Relayout C/D -> next-layer B via permlane32_swap (rows 0-15 ->
        // frag 2mt, rows 16-31 -> frag 2mt+1).
        u32x2v r02 = pls32(P[0], P[2]);
        u32x2v r13 = pls32(P[1], P[3]);
        u32x2v r46 = pls32(P[4], P[6]);
        u32x2v r57 = pls32(P[5], P[7]);
        bout[2 * mt]     = u32x4{r02[0], r13[0], r02[1], r13[1]};
        bout[2 * mt + 1] = u32x4{r46[0], r57[0], r46[1], r57[1]};
    }
}

__device__ __forceinline__ float4 ld4(const float* p) {
    float4 t;
    __builtin_memcpy(&t, p, 16);
    return t;
}

// Fetch this lane's 8 x-values (h0: k0-7, h1: k8-14 [+bias 1.0]).
__device__ __forceinline__ void fetch_x(const float* __restrict__ x, int row,
                                        int h, float4& t0, float4& t1) {
    const float* p = x + (long)row * 15;
    if (h == 0) { t0 = ld4(p);     t1 = ld4(p + 4);  }
    else        { t0 = ld4(p + 8); t1 = ld4(p + 11); }  // x8-11, x11-14
}

// Build L0's B-frag 0 (k0-15) in registers.
__device__ __forceinline__ u32x4 pack_x(float4 t0, float4 t1, int h) {
    u32x4 b;
    if (h == 0) {
        b[0] = pk2(t0.x, t0.y); b[1] = pk2(t0.z, t0.w);
        b[2] = pk2(t1.x, t1.y); b[3] = pk2(t1.z, t1.w);
    } else {
        b[0] = pk2(t0.x, t0.y); b[1] = pk2(t0.z, t0.w);
        b[2] = pk2(t1.y, t1.z); b[3] = pk2(t1.w, 1.f);   // x12,x13 | x14, bias_hi-mult
    }
    return b;
}

extern "C" __global__ void __launch_bounds__(THREADS)
mlp_fused(const float* __restrict__ x,
          const float* __restrict__ W0,  const float* __restrict__ B0,
          const float* __restrict__ W1,  const float* __restrict__ B1,
          const float* __restrict__ W2,  const float* __restrict__ B2,
          const float* __restrict__ W3,  const float* __restrict__ B3,
          const float* __restrict__ W4,  const float* __restrict__ B4,
          const float* __restrict__ W5,  const float* __restrict__ B5,
          const float* __restrict__ W6,  const float* __restrict__ B6,
          const float* __restrict__ W7,  const float* __restrict__ B7,
          const float* __restrict__ W8,  const float* __restrict__ B8,
          const float* __restrict__ W9,  const float* __restrict__ B9,
          const float* __restrict__ W10, const float* __restrict__ B10,
          float* __restrict__ out, int nchunks) {
    extern __shared__ short smem[];
    const int tid = threadIdx.x;

    stage_w<0>(W0, B0, smem, tid);
    stage_w<1>(W1, B1, smem, tid);
    stage_w<2>(W2, B2, smem, tid);
    stage_w<3>(W3, B3, smem, tid);
    stage_w<4>(W4, B4, smem, tid);
    stage_w<5>(W5, B5, smem, tid);
    stage_w<6>(W6, B6, smem, tid);
    stage_w<7>(W7, B7, smem, tid);
    stage_w<8>(W8, B8, smem, tid);
    stage_w<9>(W9, B9, smem, tid);
    stage_w<10>(W10, B10, smem, tid);
    __syncthreads();   // the only barrier in the kernel

    const int wave = tid >> 6;
    const int lane = tid & 63;
    const int n    = lane & 31;       // batch row within wave tile
    const int h    = lane >> 5;       // k-half
    const int lofs = lane * 8;        // shorts into a 512-short frag

    int chunk = blockIdx.x;
    float4 t0, t1;
    if (chunk < nchunks)
        fetch_x(x, chunk * ROWS_PER_BLOCK + wave * ROWS_PER_WAVE + n, h, t0, t1);

    for (; chunk < nchunks; chunk += gridDim.x) {
        const int row0 = chunk * ROWS_PER_BLOCK + wave * ROWS_PER_WAVE;

        u32x4 bA[8], bB[6];
        bA[0] = pack_x(t0, t1, h);
        // frag 1 (k16-31): k16 = 1.0 (L0 bias_lo multiplier), rest 0.
        bA[1] = u32x4{h == 0 ? 0x3F80u : 0u, 0u, 0u, 0u};

        // Prefetch next chunk's x while the layer stack runs.
        const int nxt = chunk + gridDim.x;
        if (nxt < nchunks)
            fetch_x(x, nxt * ROWS_PER_BLOCK + wave * ROWS_PER_WAVE + n, h, t0, t1);

        layer<0>(smem, bA, bB, lofs);   // 2 -> 2
        layer<1>(smem, bB, bA, lofs);   // 2 -> 4
        layer<2>(smem, bA, bB, lofs);   // 4 -> 6
        layer<3>(smem, bB, bA, lofs);   // 6 -> 8
        layer<4>(smem, bA, bB, lofs);   // 8 -> 6
        layer<5>(smem, bB, bA, lofs);   // 6 -> 4
        layer<6>(smem, bA, bB, lofs);   // 4 -> 2
        layer<7>(smem, bB, bA, lofs);   // 2 -> 2
        layer<8>(smem, bA, bB, lofs);   // 2 -> 2
        layer<9>(smem, bB, bA, lofs);   // 2 -> 2

        // Final layer (5 -> 1, bias via pads) + sigmoid; channel 0 lives in
        // acc[0] of lanes 0-31 (row 0, col = lane).
        {
            f32x16 acc;
#pragma unroll
            for (int i = 0; i < 16; ++i) acc[i] = 0.f;
#pragma unroll
            for (int kt = 0; kt < 2; ++kt) {
                bf16x8 af = *(const bf16x8*)(smem + WOFF_[10] + kt * 512 + lofs);
                acc = __builtin_amdgcn_mfma_f32_32x32x16_bf16(
                    af, __builtin_bit_cast(bf16x8, bA[kt]), acc, 0, 0, 0);
            }
            if (lane < 32)
                out[row0 + lane] = 1.f / (1.f + __expf(-acc[0]));
        }
    }
}

extern "C" void kernel_launch(void* const* d_in, const int* in_sizes, int n_in,
                              void* d_out, int out_size, void* d_ws, size_t ws_size,
                              hipStream_t stream) {
    (void)n_in; (void)d_ws; (void)ws_size; (void)out_size;
    const float* x = (const float*)d_in[0];
    const float* W[11];
    const float* B[11];
    for (int i = 0; i < 11; ++i) {
        W[i] = (const float*)d_in[1 + 2 * i];
        B[i] = (const float*)d_in[2 + 2 * i];
    }
    const int nrows   = in_sizes[0] / 15;
    const int nchunks = nrows / ROWS_PER_BLOCK;   // 524288/512 = 1024

    (void)hipFuncSetAttribute((const void*)mlp_fused,
                              hipFuncAttributeMaxDynamicSharedMemorySize, LDS_BYTES);

    mlp_fused<<<dim3(256), dim3(THREADS), LDS_BYTES, stream>>>(
        x,
        W[0], B[0], W[1], B[1], W[2], B[2], W[3], B[3], W[4], B[4],
        W[5], B[5], W[6], B[6], W[7], B[7], W[8], B[8], W[9], B[9],
        W[10], B[10],
        (float*)d_out, nchunks);
}

// Round 7
// 478.617 us; speedup vs baseline: 1.0063x; 1.0063x over previous
//
#include <hip/hip_runtime.h>
#include <math.h>

// ---------------------------------------------------------------------------
// Fused 11-layer funnel MLP, round 9.
// Round-8 post-mortem: design CORRECT (absmax 0.0), but missing the second
// __launch_bounds__ arg let the compiler target 8 waves/SIMD -> 64-VGPR cap
// -> the whole 14-frag activation ping-pong spilled to scratch (FETCH 658MB,
// WRITE 321MB, 380us). Fix: __launch_bounds__(1024, 4) -> 128-VGPR cap
// (16 waves, 4/SIMD), peak live ~105 regs fits.
// Structure (verified correct in r8):
//  - v_mfma_f32_32x32x16_bf16: B covers 32 rows -> 32-row weight
//    amortization inside ONE wave; 1KB A-frag per 16384 MACs.
//  - Layer chaining in REGISTERS: C/D -> next B via 2x v_permlane32_swap +
//    8x v_cvt_pk_bf16_f32 per 32-chan tile. Pure VALU, no LDS.
//  - Tail NP widened to 32 so generator rows ride inside the tile; bias via
//    hi/lo pad columns fed by 1.0-generator channels.
//  - LDS = weights only (90KB, read-only, ONE barrier total). Per 32-row
//    chunk: 90 weight b128 reads, 0 act reads, 0 writes (~69k cy/CU).
// ---------------------------------------------------------------------------

using bf16x8 = __attribute__((ext_vector_type(8))) short;   // 8 bf16 = 4 VGPRs
using f32x16 = __attribute__((ext_vector_type(16))) float;
using u32x2v = __attribute__((ext_vector_type(2))) unsigned;
using u32x4  = __attribute__((ext_vector_type(4))) unsigned;
typedef __bf16 bf16x2_t __attribute__((ext_vector_type(2)));

namespace {
constexpr int NL = 11;
constexpr int IN_[NL]   = {15, 30, 60, 90, 120, 90, 60, 30, 15, 10, 5};
constexpr int OUT_[NL]  = {30, 60, 90, 120, 90, 60, 30, 15, 10, 5, 1};
constexpr int KP_[NL]   = {32, 32, 64, 96, 128, 96, 64, 32, 32, 32, 32};  // in, pad 16-gran
constexpr int NP_[NL]   = {32, 64, 96, 128, 96, 64, 32, 32, 32, 32, 32};  // out, pad 32-gran
constexpr int WOFF_[NL] = {0, 1024, 3072, 9216, 21504, 33792, 39936,
                           41984, 43008, 44032, 45056};
constexpr int WTOT      = 46080;                     // shorts (90 KB)
constexpr int WAVES     = 16;
constexpr int THREADS   = WAVES * 64;                // 1024
constexpr int ROWS_PER_WAVE  = 32;
constexpr int ROWS_PER_BLOCK = WAVES * ROWS_PER_WAVE; // 512
constexpr int LDS_BYTES = WTOT * 2;                  // 92160
}

// fp32 -> bf16 RNE (scalar, staging only)
__device__ __forceinline__ unsigned short f2bf(float f) {
    unsigned u = __float_as_uint(f);
    u += 0x7fffu + ((u >> 16) & 1u);
    return (unsigned short)(u >> 16);
}

// packed fp32x2 -> bf16x2 (RNE); gfx950 has v_cvt_pk_bf16_f32
__device__ __forceinline__ unsigned pk2(float a, float b) {
#if __has_builtin(__builtin_amdgcn_cvt_pk_bf16_f32)
    return __builtin_bit_cast(unsigned, __builtin_amdgcn_cvt_pk_bf16_f32(a, b));
#else
    bf16x2_t c;
    c[0] = (__bf16)a;
    c[1] = (__bf16)b;
    return __builtin_bit_cast(unsigned, c);
#endif
}

// permlane32_swap: r[0] = [a_lo, b_lo], r[1] = [a_hi, b_hi]  (VALU, no LDS)
__device__ __forceinline__ u32x2v pls32(unsigned a, unsigned b) {
#if __has_builtin(__builtin_amdgcn_permlane32_swap)
    auto t = __builtin_amdgcn_permlane32_swap(a, b, false, false);
    u32x2v r;
    r[0] = t[0];
    r[1] = t[1];
    return r;
#else
    const int l = (int)(threadIdx.x & 63);
    unsigned bl = (unsigned)__shfl((int)b, l & 31, 64);
    unsigned ah = (unsigned)__shfl((int)a, l | 32, 64);
    u32x2v r;
    r[0] = (l < 32) ? a : bl;
    r[1] = (l < 32) ? ah : b;
    return r;
#endif
}

// Stage layer L's weights as 32x32x16 A-frags (frag-major, 512 shorts/frag).
// A[m][k]: lane = (k_local>>3)*32 + m_local, j = k_local&7.
// Bias folded as pad columns: k==IN -> bias_hi, k==IN+1 -> bias_lo.
// Generator rows m==OUT, OUT+1 emit 1.0 (feed next layer's bias columns).
template <int L>
__device__ __forceinline__ void stage_w(const float* __restrict__ W,
                                        const float* __restrict__ B,
                                        short* wlds, int tid) {
    constexpr int KP = KP_[L], NP = NP_[L], INl = IN_[L], OUTl = OUT_[L];
    constexpr int NKT = KP / 16;
    for (int idx = tid; idx < NP * KP; idx += THREADS) {
        const int f    = idx >> 9;
        const int t    = idx & 511;
        const int ln   = t >> 3;
        const int j    = t & 7;
        const int mloc = ln & 31;
        const int kh   = ln >> 5;
        const int mt   = f / NKT;
        const int kt   = f - mt * NKT;
        const int m    = mt * 32 + mloc;
        const int k    = kt * 16 + kh * 8 + j;
        float v = 0.f;
        if (m < OUTl) {
            if (k < INl) v = W[m * INl + k];
            else if (k == INl) v = B[m];                    // bias_hi
            else if (k == INl + 1) {                        // bias_lo
                float hf = __builtin_bit_cast(float, (unsigned)f2bf(B[m]) << 16);
                v = B[m] - hf;
            }
        } else if (m == OUTl || m == OUTl + 1) {
            if (k == INl) v = 1.f;                          // 1.0-generator row
        }
        wlds[WOFF_[L] + idx] = (short)f2bf(v);
    }
}

// One Linear+ReLU layer over this wave's 32 rows, fully in registers.
// bin: KP/16 input B-frags; bout: 2*NMT output B-frags (= next layer's bin).
template <int L>
__device__ __forceinline__ void layer(const short* __restrict__ wlds,
                                      const u32x4* bin, u32x4* bout, int lofs) {
    constexpr int NKT = KP_[L] / 16;
    constexpr int NMT = NP_[L] / 32;
    const short* wl = wlds + WOFF_[L];
#pragma unroll
    for (int mt = 0; mt < NMT; ++mt) {
        f32x16 acc;
#pragma unroll
        for (int i = 0; i < 16; ++i) acc[i] = 0.f;
#pragma unroll
        for (int kt = 0; kt < NKT; ++kt) {
            bf16x8 af = *(const bf16x8*)(wl + (mt * NKT + kt) * 512 + lofs);
            acc = __builtin_amdgcn_mfma_f32_32x32x16_bf16(
                af, __builtin_bit_cast(bf16x8, bin[kt]), acc, 0, 0, 0);
        }
        // ReLU + pack reg-pairs.
        unsigned P[8];
#pragma unroll
        for (int i = 0; i < 8; ++i)
            P[i] = pk2(fmaxf(acc[2 * i], 0.f), fmaxf(acc[2 * i + 1], 0.f));
        // Relayout C/D -> next-layer B via permlane32_swap (rows 0-15 ->
        // frag 2mt, rows 16-31 -> frag 2mt+1).
        u32x2v r02 = pls32(P[0], P[2]);
        u32x2v r13 = pls32(P[1], P[3]);
        u32x2v r46 = pls32(P[4], P[6]);
        u32x2v r57 = pls32(P[5], P[7]);
        bout[2 * mt]     = u32x4{r02[0], r13[0], r02[1], r13[1]};
        bout[2 * mt + 1] = u32x4{r46[0], r57[0], r46[1], r57[1]};
    }
}

__device__ __forceinline__ float4 ld4(const float* p) {
    float4 t;
    __builtin_memcpy(&t, p, 16);
    return t;
}

// Fetch this lane's 8 x-values (h0: k0-7, h1: k8-14 [+bias 1.0]).
__device__ __forceinline__ void fetch_x(const float* __restrict__ x, int row,
                                        int h, float4& t0, float4& t1) {
    const float* p = x + (long)row * 15;
    if (h == 0) { t0 = ld4(p);     t1 = ld4(p + 4);  }
    else        { t0 = ld4(p + 8); t1 = ld4(p + 11); }  // x8-11, x11-14
}

// Build L0's B-frag 0 (k0-15) in registers.
__device__ __forceinline__ u32x4 pack_x(float4 t0, float4 t1, int h) {
    u32x4 b;
    if (h == 0) {
        b[0] = pk2(t0.x, t0.y); b[1] = pk2(t0.z, t0.w);
        b[2] = pk2(t1.x, t1.y); b[3] = pk2(t1.z, t1.w);
    } else {
        b[0] = pk2(t0.x, t0.y); b[1] = pk2(t0.z, t0.w);
        b[2] = pk2(t1.y, t1.z); b[3] = pk2(t1.w, 1.f);   // x12,x13 | x14, bias_hi-mult
    }
    return b;
}

extern "C" __global__ void __launch_bounds__(THREADS, 4)
mlp_fused(const float* __restrict__ x,
          const float* __restrict__ W0,  const float* __restrict__ B0,
          const float* __restrict__ W1,  const float* __restrict__ B1,
          const float* __restrict__ W2,  const float* __restrict__ B2,
          const float* __restrict__ W3,  const float* __restrict__ B3,
          const float* __restrict__ W4,  const float* __restrict__ B4,
          const float* __restrict__ W5,  const float* __restrict__ B5,
          const float* __restrict__ W6,  const float* __restrict__ B6,
          const float* __restrict__ W7,  const float* __restrict__ B7,
          const float* __restrict__ W8,  const float* __restrict__ B8,
          const float* __restrict__ W9,  const float* __restrict__ B9,
          const float* __restrict__ W10, const float* __restrict__ B10,
          float* __restrict__ out, int nchunks) {
    extern __shared__ short smem[];
    const int tid = threadIdx.x;

    stage_w<0>(W0, B0, smem, tid);
    stage_w<1>(W1, B1, smem, tid);
    stage_w<2>(W2, B2, smem, tid);
    stage_w<3>(W3, B3, smem, tid);
    stage_w<4>(W4, B4, smem, tid);
    stage_w<5>(W5, B5, smem, tid);
    stage_w<6>(W6, B6, smem, tid);
    stage_w<7>(W7, B7, smem, tid);
    stage_w<8>(W8, B8, smem, tid);
    stage_w<9>(W9, B9, smem, tid);
    stage_w<10>(W10, B10, smem, tid);
    __syncthreads();   // the only barrier in the kernel

    const int wave = tid >> 6;
    const int lane = tid & 63;
    const int n    = lane & 31;       // batch row within wave tile
    const int h    = lane >> 5;       // k-half
    const int lofs = lane * 8;        // shorts into a 512-short frag

    int chunk = blockIdx.x;
    float4 t0, t1;
    if (chunk < nchunks)
        fetch_x(x, chunk * ROWS_PER_BLOCK + wave * ROWS_PER_WAVE + n, h, t0, t1);

    for (; chunk < nchunks; chunk += gridDim.x) {
        const int row0 = chunk * ROWS_PER_BLOCK + wave * ROWS_PER_WAVE;

        u32x4 bA[8], bB[6];
        bA[0] = pack_x(t0, t1, h);
        // frag 1 (k16-31): k16 = 1.0 (L0 bias_lo multiplier), rest 0.
        bA[1] = u32x4{h == 0 ? 0x3F80u : 0u, 0u, 0u, 0u};

        // Prefetch next chunk's x while the layer stack runs.
        const int nxt = chunk + gridDim.x;
        if (nxt < nchunks)
            fetch_x(x, nxt * ROWS_PER_BLOCK + wave * ROWS_PER_WAVE + n, h, t0, t1);

        layer<0>(smem, bA, bB, lofs);   // 2 -> 2
        layer<1>(smem, bB, bA, lofs);   // 2 -> 4
        layer<2>(smem, bA, bB, lofs);   // 4 -> 6
        layer<3>(smem, bB, bA, lofs);   // 6 -> 8
        layer<4>(smem, bA, bB, lofs);   // 8 -> 6
        layer<5>(smem, bB, bA, lofs);   // 6 -> 4
        layer<6>(smem, bA, bB, lofs);   // 4 -> 2
        layer<7>(smem, bB, bA, lofs);   // 2 -> 2
        layer<8>(smem, bA, bB, lofs);   // 2 -> 2
        layer<9>(smem, bB, bA, lofs);   // 2 -> 2

        // Final layer (5 -> 1, bias via pads) + sigmoid; channel 0 lives in
        // acc[0] of lanes 0-31 (row 0, col = lane).
        {
            f32x16 acc;
#pragma unroll
            for (int i = 0; i < 16; ++i) acc[i] = 0.f;
#pragma unroll
            for (int kt = 0; kt < 2; ++kt) {
                bf16x8 af = *(const bf16x8*)(smem + WOFF_[10] + kt * 512 + lofs);
                acc = __builtin_amdgcn_mfma_f32_32x32x16_bf16(
                    af, __builtin_bit_cast(bf16x8, bA[kt]), acc, 0, 0, 0);
            }
            if (lane < 32)
                out[row0 + lane] = 1.f / (1.f + __expf(-acc[0]));
        }
    }
}

extern "C" void kernel_launch(void* const* d_in, const int* in_sizes, int n_in,
                              void* d_out, int out_size, void* d_ws, size_t ws_size,
                              hipStream_t stream) {
    (void)n_in; (void)d_ws; (void)ws_size; (void)out_size;
    const float* x = (const float*)d_in[0];
    const float* W[11];
    const float* B[11];
    for (int i = 0; i < 11; ++i) {
        W[i] = (const float*)d_in[1 + 2 * i];
        B[i] = (const float*)d_in[2 + 2 * i];
    }
    const int nrows   = in_sizes[0] / 15;
    const int nchunks = nrows / ROWS_PER_BLOCK;   // 524288/512 = 1024

    (void)hipFuncSetAttribute((const void*)mlp_fused,
                              hipFuncAttributeMaxDynamicSharedMemorySize, LDS_BYTES);

    mlp_fused<<<dim3(256), dim3(THREADS), LDS_BYTES, stream>>>(
        x,
        W[0], B[0], W[1], B[1], W[2], B[2], W[3], B[3], W[4], B[4],
        W[5], B[5], W[6], B[6], W[7], B[7], W[8], B[8], W[9], B[9],
        W[10], B[10],
        (float*)d_out, nchunks);
}